// Round 14
// baseline (264.265 us; speedup 1.0000x reference)
//
#include <hip/hip_runtime.h>
#include <hip/hip_bf16.h>
#include <stdint.h>

#define M_DIM 8192   // 4*2048
#define N_DIM 4096   // OUT_FEATURES
#define K_DIM 4096   // IN_FEATURES

typedef __attribute__((ext_vector_type(8))) __bf16 bf16x8;
typedef __attribute__((ext_vector_type(4))) float  f32x4;

#define GLD_LDS16(gaddr, laddr)                                            \
  __builtin_amdgcn_global_load_lds(                                        \
      (const __attribute__((address_space(1))) uint32_t*)(gaddr),          \
      (__attribute__((address_space(3))) uint32_t*)(laddr), 16, 0, 0)

// ---------------------------------------------------------------------------
// Subtile-major layout for 16x16x32 fragments (both Xf and Wf):
//  t = k>>6 (K-tile); rp = row>>8; h = (row>>7)&1; f = (row>>4)&7;
//  ks = (k>>5)&1; l = (row&15) | (((k>>3)&3)<<4)
//  byte = (rp*64+t)*32768 + h*16384 + (f*2+ks)*1024 + l*16
// ---------------------------------------------------------------------------

// Merged prep: blocks [0,2048) dequant qweight -> Wf; [2048,18432) cvt x -> Xf.
__global__ __launch_bounds__(256) void prep_kernel(
    const int* __restrict__ q, const float* __restrict__ lut,
    __bf16* __restrict__ Wf,
    const float* __restrict__ x, __bf16* __restrict__ Xf) {
  __shared__ char sm[16384];
  const int b = blockIdx.x;
  const int tid = threadIdx.x;
  if (b < 2048) {
    const int ob = b >> 4, wb = b & 15;
    const int o0 = ob * 32, w0 = wb * 8;
    const int o_l = tid >> 3, w_l = tid & 7;
    const int o = o0 + o_l;
    const int PLANE = N_DIM * (K_DIM / 32);
    const int base = o * (K_DIM / 32) + (w0 + w_l);
    uint32_t q0 = (uint32_t)q[base];
    uint32_t q1 = (uint32_t)q[PLANE + base];
    uint32_t q2 = (uint32_t)q[2 * PLANE + base];
    uint32_t q3 = (uint32_t)q[3 * PLANE + base];
    const float* lrow = lut + o * 16;
    const int t_local = w_l >> 1;        // 0..3
    const int ks = w_l & 1;
    const int f_local = o_l >> 4;        // 0..1
#pragma unroll
    for (int g = 0; g < 4; ++g) {
      bf16x8 v;
#pragma unroll
      for (int j = 0; j < 8; ++j) {
        const int i = g * 8 + j;
        uint32_t idx = ((q0 >> i) & 1u) | (((q1 >> i) & 1u) << 1) |
                       (((q2 >> i) & 1u) << 2) | (((q3 >> i) & 1u) << 3);
        v[j] = (__bf16)lrow[idx];
      }
      const int l = (o_l & 15) | (g << 4);
      *(bf16x8*)(sm + t_local * 4096 + (f_local * 2 + ks) * 1024 + l * 16) = v;
    }
    __syncthreads();
    const int rp = ob >> 3, h = (ob >> 2) & 1, f0 = (ob * 2) & 7;
#pragma unroll
    for (int c = 0; c < 4; ++c) {
      const size_t outb = ((size_t)(rp * 64 + wb * 4 + c)) * 32768
                          + h * 16384 + f0 * 2048;
      *(bf16x8*)((char*)Wf + outb + tid * 16) = *(bf16x8*)(sm + c * 4096 + tid * 16);
    }
  } else {
    const int bb = b - 2048;
    const int rb = bb >> 6, t = bb & 63;
    const int row0 = rb * 32;
    const int r_l = tid >> 3, k8 = tid & 7;
    const float* src = x + (size_t)(row0 + r_l) * K_DIM + t * 64 + k8 * 8;
    f32x4 u = *(const f32x4*)src;
    f32x4 w4 = *(const f32x4*)(src + 4);
    bf16x8 v;
    v[0] = (__bf16)u[0];  v[1] = (__bf16)u[1];  v[2] = (__bf16)u[2];  v[3] = (__bf16)u[3];
    v[4] = (__bf16)w4[0]; v[5] = (__bf16)w4[1]; v[6] = (__bf16)w4[2]; v[7] = (__bf16)w4[3];
    const int f_local = r_l >> 4, ks = k8 >> 2;
    const int l = (r_l & 15) | ((k8 & 3) << 4);
    *(bf16x8*)(sm + (f_local * 2 + ks) * 1024 + l * 16) = v;
    __syncthreads();
    const int rp = rb >> 3, h = (rb >> 2) & 1, f0 = (rb * 2) & 7;
    const size_t outb = ((size_t)(rp * 64 + t)) * 32768 + h * 16384 + f0 * 2048;
    *(bf16x8*)((char*)Xf + outb + tid * 16) = *(bf16x8*)(sm + tid * 16);
  }
}

// ---------------------------------------------------------------------------
// 256x256 bf16 GEMM, R14: RACE-FREE 3-barrier/tile schedule, linear LDS.
// Per tile t (buf c=t&1, nb=(t+1)&1):
//  P12: stage B0(t+1),A0(t+2); read b1,a1(t); MMA(0,0)+(0,1); lgkm0 bar
//  p3 : stage B1(t+2); MMA(1,1); lgkm0 VMC(4) bar   [certifies tile t+1 FULLY:
//       drains A0(t+1)@P12(t-1), B1(t+1)@p3(t-1), A1(t+1)@p4(t-1), B0(t+1)@P12(t)]
//  p4 : stage A1(t+2); read a0,b0(t+1) [post-cert]; MMA(1,0); lgkm0 bar
// All stage-overwrite WAR windows closed by lgkm0+bar >=1 barrier earlier.
// ---------------------------------------------------------------------------
__global__ __launch_bounds__(512, 2) void anyprec_gemm_kernel(
    const __bf16* __restrict__ A,   // subtile-major Xf
    const __bf16* __restrict__ B,   // subtile-major Wf
    const float* __restrict__ bias,
    float* __restrict__ C) {
  __shared__ __bf16 lds[2][2][2][8192];   // [buf][mat][half][16KB] = 128 KiB

  int bid = blockIdx.x;
  int swz = (bid & 7) * 64 + (bid >> 3);
  int mb = swz >> 4;    // 32 m-tiles
  int nb = swz & 15;    // 16 n-tiles

  const int tid  = threadIdx.x;
  const int lane = tid & 63;
  const int wid  = tid >> 6;
  const int wr   = wid >> 2;   // 0..1
  const int wc   = wid & 3;    // 0..3
  const int tid16  = tid * 16;
  const int lane16 = lane * 16;

  const char* gA = (const char*)A + (size_t)mb * 2097152;  // 64 tiles * 32KB
  const char* gB = (const char*)B + (size_t)nb * 2097152;

  f32x4 acc[2][2][4][2];
#pragma unroll
  for (int qm = 0; qm < 2; ++qm)
#pragma unroll
    for (int qn = 0; qn < 2; ++qn)
#pragma unroll
      for (int mf = 0; mf < 4; ++mf)
#pragma unroll
        for (int nf = 0; nf < 2; ++nf) acc[qm][qn][mf][nf] = (f32x4)0.0f;

  bf16x8 a0[4][2], a1[4][2], b0[2][2], b1[2][2];

#define STAGE(mat, h, buf, t) {                                            \
    char* lb_ = (char*)&lds[buf][mat][h][0] + tid16;                       \
    const char* gb_ = (mat ? gB : gA) + (size_t)(t) * 32768                \
                      + (h) * 16384 + tid16;                               \
    GLD_LDS16(gb_,        lb_);                                            \
    GLD_LDS16(gb_ + 8192, lb_ + 8192); }

#define LDA(dst, qm, buf) {                                                \
    const char* p_ = (const char*)&lds[buf][0][qm][0] + wr * 8192          \
                     + lane16;                                             \
    _Pragma("unroll")                                                      \
    for (int mf = 0; mf < 4; ++mf) {                                       \
      dst[mf][0] = *(const bf16x8*)(p_ + mf * 2048);                       \
      dst[mf][1] = *(const bf16x8*)(p_ + mf * 2048 + 1024); } }

#define LDB(dst, qn, buf) {                                                \
    const char* p_ = (const char*)&lds[buf][1][qn][0] + wc * 4096          \
                     + lane16;                                             \
    _Pragma("unroll")                                                      \
    for (int nf = 0; nf < 2; ++nf) {                                       \
      dst[nf][0] = *(const bf16x8*)(p_ + nf * 2048);                       \
      dst[nf][1] = *(const bf16x8*)(p_ + nf * 2048 + 1024); } }

#define MMA(qm, qn, aa, bb) {                                              \
    _Pragma("unroll")                                                      \
    for (int mf = 0; mf < 4; ++mf)                                         \
      _Pragma("unroll")                                                    \
      for (int nf = 0; nf < 2; ++nf) {                                     \
        acc[qm][qn][mf][nf] = __builtin_amdgcn_mfma_f32_16x16x32_bf16(     \
            aa[mf][0], bb[nf][0], acc[qm][qn][mf][nf], 0, 0, 0);           \
        acc[qm][qn][mf][nf] = __builtin_amdgcn_mfma_f32_16x16x32_bf16(     \
            aa[mf][1], bb[nf][1], acc[qm][qn][mf][nf], 0, 0, 0); } }

#define PRIO1 __builtin_amdgcn_s_setprio(1);
#define PRIO0 __builtin_amdgcn_s_setprio(0);
#define BAR   __builtin_amdgcn_s_barrier();
#define LGKM0 asm volatile("s_waitcnt lgkmcnt(0)" ::: "memory");
#define VMC(n) asm volatile("s_waitcnt vmcnt(" #n ")" ::: "memory");

  // ---- prologue: tile0 (8 loads) + A0(1),B1(1),A1(1) (6 loads); cert tile0
  STAGE(0, 0, 0, 0); STAGE(1, 0, 0, 0);   // A0(0), B0(0)
  STAGE(0, 1, 0, 0); STAGE(1, 1, 0, 0);   // A1(0), B1(0)
  STAGE(0, 0, 1, 1);                      // A0(1)
  STAGE(1, 1, 1, 1);                      // B1(1)
  STAGE(0, 1, 1, 1);                      // A1(1)
  VMC(6); BAR;                            // tile0 certified collectively
  LDA(a0, 0, 0); LDB(b0, 0, 0);
  LGKM0; BAR;   // rpeload drained before P12(0)'s A0(2) stage overwrites buf0.A0

  // ---- main loop: t = 0..61
  for (int t = 0; t < 62; ++t) {
    const int c = t & 1, n = (t + 1) & 1;
    // P12(t)
    STAGE(1, 0, n, t + 1);                // B0(t+1)
    STAGE(0, 0, c, t + 2);                // A0(t+2)
    PRIO1; LDB(b1, 1, c); MMA(0, 0, a0, b0);
    LDA(a1, 1, c); MMA(0, 1, a0, b1); PRIO0;
    LGKM0; BAR;
    // p3(t)
    STAGE(1, 1, c, t + 2);                // B1(t+2)
    PRIO1; MMA(1, 1, a1, b1); PRIO0;
    LGKM0; VMC(4); BAR;                   // tile t+1 certified collectively
    // p4(t)
    STAGE(0, 1, c, t + 2);                // A1(t+2)
    PRIO1; LDA(a0, 0, n); MMA(1, 0, a1, b0); LDB(b0, 0, n); PRIO0;
    LGKM0; BAR;
  }

  // ---- tail: t = 62 (buf0), t = 63 (buf1)
  // P12(62)
  STAGE(1, 0, 1, 63);                     // B0(63)
  PRIO1; LDB(b1, 1, 0); MMA(0, 0, a0, b0);
  LDA(a1, 1, 0); MMA(0, 1, a0, b1); PRIO0;
  LGKM0; BAR;
  // p3(62)
  PRIO1; MMA(1, 1, a1, b1); PRIO0;
  LGKM0; VMC(0); BAR;                     // tile 63 fully certified
  // p4(62)
  PRIO1; LDA(a0, 0, 1); MMA(1, 0, a1, b0); LDB(b0, 0, 1); PRIO0;
  LGKM0; BAR;
  // t = 63 (no stages, no barriers needed)
  PRIO1; LDB(b1, 1, 1); MMA(0, 0, a0, b0);
  LDA(a1, 1, 1); MMA(0, 1, a0, b1);
  MMA(1, 1, a1, b1);
  MMA(1, 0, a1, b0); PRIO0;

  // ---- epilogue: C/D layout col=lane&15, row=(lane>>4)*4+j
  const int cL = lane & 15;
  const int rL = (lane >> 4) * 4;
#pragma unroll
  for (int qn = 0; qn < 2; ++qn)
#pragma unroll
    for (int nf = 0; nf < 2; ++nf) {
      int col = nb * 256 + qn * 128 + wc * 32 + nf * 16 + cL;
      float bv = bias[col];
#pragma unroll
      for (int qm = 0; qm < 2; ++qm)
#pragma unroll
        for (int mf = 0; mf < 4; ++mf) {
          int row0 = mb * 256 + qm * 128 + wr * 64 + mf * 16 + rL;
#pragma unroll
          for (int j = 0; j < 4; ++j)
            C[(size_t)(row0 + j) * N_DIM + col] = acc[qm][qn][mf][nf][j] + bv;
        }
    }
#undef STAGE
#undef LDA
#undef LDB
#undef MMA
#undef PRIO1
#undef PRIO0
#undef BAR
#undef LGKM0
#undef VMC
}

extern "C" void kernel_launch(void* const* d_in, const int* in_sizes, int n_in,
                              void* d_out, int out_size, void* d_ws, size_t ws_size,
                              hipStream_t stream) {
  const float* x    = (const float*)d_in[0];
  const int*   qw   = (const int*)d_in[1];
  const float* lut  = (const float*)d_in[2];
  const float* bias = (const float*)d_in[3];

  __bf16* Wf = (__bf16*)d_ws;                                       // 32 MB
  __bf16* Xf = (__bf16*)((char*)d_ws + (size_t)N_DIM * K_DIM * 2);  // 64 MB

  {
    prep_kernel<<<18432, 256, 0, stream>>>(qw, lut, Wf, x, Xf);
  }
  {
    dim3 grid((M_DIM / 256) * (N_DIM / 256));  // 32*16 = 512
    anyprec_gemm_kernel<<<grid, 512, 0, stream>>>(Xf, Wf, bias, (float*)d_out);
  }
}